// Round 16
// baseline (110.891 us; speedup 1.0000x reference)
//
#include <hip/hip_runtime.h>
#include <math.h>

#define PAD_IDX 0
#define BIGV 10000.0f
constexpr int B_ = 1024, S_ = 128, V_ = 200, E_ = 512, H_ = 512, T_ = 24;

// ws layout (float offsets):
constexpr int OFF_H  = 262144;   // h_ws   [200][512]
constexpr int OFF_EM = 364544;   // em_tab [200][24]
constexpr int OFF_W  = 369344;   // w_tab  [200][24]
constexpr int OFF_MX = 374144;   // emax   [200]

typedef __attribute__((ext_vector_type(8)))  short    bf8frag;   // 8 bf16
typedef __attribute__((ext_vector_type(16))) float    facc16;    // MFMA C/D
typedef __attribute__((ext_vector_type(4)))  unsigned u32x4;

__device__ __forceinline__ unsigned pkbf(float lo, float hi) {
    const unsigned a = __float_as_uint(lo), b = __float_as_uint(hi);
    return ((a + 0x8000u) >> 16) | ((b + 0x8000u) & 0xffff0000u);
}

// ---------------------------------------------------------------------------
// Kernel M1: h = relu(emb @ w1^T + b1) on the matrix pipe (R15, verified).
// ---------------------------------------------------------------------------
__global__ __launch_bounds__(256) void mlp1_kernel(
    const float* __restrict__ emb, const float* __restrict__ w1,
    const float* __restrict__ b1, float* __restrict__ h_ws,
    float* __restrict__ out)
{
    __shared__ unsigned w1b[256][32];     // B operand: [kp][t-col]
    __shared__ unsigned embb[256][32];    // A operand: [kp][v-row]
    __shared__ float    part[4][64][17];  // K-split partials (+1 pad)
    const int tid = threadIdx.x;
    const int vt = blockIdx.x % 7, tt = blockIdx.x / 7;
    const int v0 = vt * 32, t0 = tt * 32;

    if (blockIdx.x == 0 && tid == 0) out[0] = 0.f;   // crf atomic accumulator

    {
        const int row = tid >> 3;          // 0..31
        const int seg = tid & 7;           // 64 floats each
        {
            const float* __restrict__ src = w1 + (size_t)(t0 + row) * E_ + seg * 64;
            #pragma unroll
            for (int i = 0; i < 16; ++i) {
                const float4 f = *(const float4*)(src + i * 4);
                const int kp = seg * 32 + i * 2;
                w1b[kp][row]     = pkbf(f.x, f.y);
                w1b[kp + 1][row] = pkbf(f.z, f.w);
            }
        }
        const int v = v0 + row;
        if (v < V_) {
            const float* __restrict__ src = emb + (size_t)v * E_ + seg * 64;
            #pragma unroll
            for (int i = 0; i < 16; ++i) {
                const float4 f = *(const float4*)(src + i * 4);
                const int kp = seg * 32 + i * 2;
                embb[kp][row]     = pkbf(f.x, f.y);
                embb[kp + 1][row] = pkbf(f.z, f.w);
            }
        } else {
            #pragma unroll
            for (int i = 0; i < 16; ++i) {
                const int kp = seg * 32 + i * 2;
                embb[kp][row] = 0u; embb[kp + 1][row] = 0u;
            }
        }
    }
    __syncthreads();

    {
        const int wave = tid >> 6, lane = tid & 63;
        const int mn = lane & 31, h2 = lane >> 5;
        facc16 acc;
        #pragma unroll
        for (int r = 0; r < 16; ++r) acc[r] = 0.f;
        #pragma unroll
        for (int c = 0; c < 8; ++c) {
            const int kp = wave * 64 + c * 8 + 4 * h2;
            u32x4 Af, Bf;
            #pragma unroll
            for (int r = 0; r < 4; ++r) {
                Af[r] = embb[kp + r][mn];
                Bf[r] = w1b[kp + r][mn];
            }
            acc = __builtin_amdgcn_mfma_f32_32x32x16_bf16(
                      __builtin_bit_cast(bf8frag, Af),
                      __builtin_bit_cast(bf8frag, Bf), acc, 0, 0, 0);
        }
        #pragma unroll
        for (int r = 0; r < 16; ++r) part[wave][lane][r] = acc[r];
    }
    __syncthreads();

    {
        const int l = tid & 63, rg = tid >> 6;
        const int col = l & 31, hh = l >> 5;
        const float bb = b1[t0 + col];
        #pragma unroll
        for (int i = 0; i < 4; ++i) {
            const int r = rg * 4 + i;
            const float s = (part[0][l][r] + part[1][l][r])
                          + (part[2][l][r] + part[3][l][r]);
            const int vrow = (r & 3) + 8 * (r >> 2) + 4 * hh;
            const int v = v0 + vrow;
            if (v < V_)
                h_ws[(size_t)v * H_ + t0 + col] = fmaxf(s + bb, 0.f);
        }
    }
}

// ---------------------------------------------------------------------------
// Kernel A2 (R16): emis on the MATRIX pipe. 25 blocks x 8 v-rows (200=25x8).
// A = h tile bf16 [kp][vrow] (rows 8..31 zero), B = w2 [kp][tcol] (cols
// 24..31 zero), K=512 split 4 waves x 8 chained MFMAs. Only C-regs 0..3
// carry valid v-rows (vrow = r + 4h < 8). Bias+relu+BIG, per-row max, exp
// table; em/w stores are linear in tid (coalesced). Fragment recipe is the
// mlp1/R11 HW-verified one. Replaces the 2.5us VALU split-K emis.
// ---------------------------------------------------------------------------
__global__ __launch_bounds__(256) void emis_kernel(
    const float* __restrict__ h_ws, const float* __restrict__ w2,
    const float* __restrict__ b2, float* __restrict__ em_table,
    float* __restrict__ w_table, float* __restrict__ emax_arr)
{
    __shared__ unsigned hA[256][32];      // A: [kp][vrow]
    __shared__ unsigned w2B[256][32];     // B: [kp][tcol]
    __shared__ float    part[4][64][5];   // only regs 0..3 needed (+1 pad)
    __shared__ float    em_t[8][33];
    __shared__ float    mx_s[8];
    const int tid = threadIdx.x;
    const int v0 = blockIdx.x * 8;

    // stage h rows (8 x 512) -> A layout
    {
        const int row = tid >> 5;          // 0..7
        const int seg = tid & 31;          // 16 floats each
        const float* __restrict__ src = h_ws + (size_t)(v0 + row) * H_ + seg * 16;
        #pragma unroll
        for (int i = 0; i < 4; ++i) {
            const float4 f = *(const float4*)(src + i * 4);
            const int kp = seg * 8 + i * 2;
            hA[kp][row]     = pkbf(f.x, f.y);
            hA[kp + 1][row] = pkbf(f.z, f.w);
        }
        for (int idx = tid; idx < 256 * 24; idx += 256) {
            const int kp = idx / 24, rz = 8 + idx % 24;
            hA[kp][rz] = 0u;
        }
    }
    // stage w2 (24 x 512) -> B layout
    {
        if (tid < 192) {
            const int row = tid >> 3;      // 0..23
            const int seg = tid & 7;       // 64 floats each
            const float* __restrict__ src = w2 + (size_t)row * H_ + seg * 64;
            #pragma unroll
            for (int i = 0; i < 16; ++i) {
                const float4 f = *(const float4*)(src + i * 4);
                const int kp = seg * 32 + i * 2;
                w2B[kp][row]     = pkbf(f.x, f.y);
                w2B[kp + 1][row] = pkbf(f.z, f.w);
            }
        }
        for (int idx = tid; idx < 256 * 8; idx += 256) {
            const int kp = idx >> 3, cz = 24 + (idx & 7);
            w2B[kp][cz] = 0u;
        }
    }
    __syncthreads();

    // K-split MFMA: wave w covers k in [w*128, w*128+128)
    {
        const int wave = tid >> 6, lane = tid & 63;
        const int mn = lane & 31, h2 = lane >> 5;
        facc16 acc;
        #pragma unroll
        for (int r = 0; r < 16; ++r) acc[r] = 0.f;
        #pragma unroll
        for (int c = 0; c < 8; ++c) {
            const int kp = wave * 64 + c * 8 + 4 * h2;
            u32x4 Af, Bf;
            #pragma unroll
            for (int r = 0; r < 4; ++r) {
                Af[r] = hA[kp + r][mn];
                Bf[r] = w2B[kp + r][mn];
            }
            acc = __builtin_amdgcn_mfma_f32_32x32x16_bf16(
                      __builtin_bit_cast(bf8frag, Af),
                      __builtin_bit_cast(bf8frag, Bf), acc, 0, 0, 0);
        }
        #pragma unroll
        for (int r = 0; r < 4; ++r) part[wave][lane][r] = acc[r];
    }
    __syncthreads();

    // combine + bias + relu + BIG -> em_t[vrow][col]
    if (tid < 64) {
        const int col = tid & 31, h2 = tid >> 5;
        #pragma unroll
        for (int r = 0; r < 4; ++r) {
            const float s = (part[0][tid][r] + part[1][tid][r])
                          + (part[2][tid][r] + part[3][tid][r]);
            const int vrow = r + 4 * h2;       // 0..7
            if (col < T_) {
                float val = fmaxf(s + b2[col], 0.f);
                if (v0 == 0 && vrow == 0 && col == PAD_IDX) val += BIGV;
                em_t[vrow][col] = val;
            }
        }
    }
    __syncthreads();
    if (tid < 8) {
        float mx = em_t[tid][0];
        #pragma unroll
        for (int c = 1; c < T_; ++c) mx = fmaxf(mx, em_t[tid][c]);
        mx_s[tid] = mx;
        emax_arr[v0 + tid] = mx;
    }
    __syncthreads();
    if (tid < 8 * T_) {
        const int r = tid / T_, c = tid % T_;
        const float em = em_t[r][c];
        em_table[v0 * T_ + tid] = em;                  // linear in tid
        w_table[v0 * T_ + tid]  = __expf(em - mx_s[r]);
    }
}

// ---------------------------------------------------------------------------
// Kernel B: crf + gold fused (R14/R15, passed absmax 0.0, unchanged).
// ---------------------------------------------------------------------------
__global__ __launch_bounds__(256) void crf_kernel(
    const int* __restrict__ seq, const int* __restrict__ labels,
    const float* __restrict__ start_t, const float* __restrict__ end_t,
    const float* __restrict__ trans, const float* __restrict__ em_table,
    const float* __restrict__ w_table, const float* __restrict__ emax_arr,
    float* __restrict__ out)
{
    __shared__ __align__(16) float w_s[V_ * T_];
    __shared__ int   tok_s[S_ * 32];
    __shared__ float meet_s[64 * 12];
    __shared__ float logb_s[64];
    __shared__ float gp_s[32];
    const int tid = threadIdx.x;
    const int g = blockIdx.x;

    for (int i = tid; i < V_ * T_ / 4; i += 256)
        ((float4*)w_s)[i] = ((const float4*)w_table)[i];
    {
        const int bq = tid & 31, c = tid >> 5;
        const int* __restrict__ src = seq + (size_t)(g * 32 + bq) * S_ + c * 16;
        #pragma unroll
        for (int i = 0; i < 16; ++i)
            tok_s[(c * 16 + i) * 32 + bq] = src[i];
    }
    if (tid < 32) gp_s[tid] = 0.f;
    __syncthreads();

    if (tid < 128) {
        const bool isF = (tid < 64);
        const int lane = tid & 63;
        const int n = lane & 31;
        const int h = lane >> 5;

        u32x4 A1p, A2p;
        {
            float a1e[8], a2e[8];
            #pragma unroll
            for (int j = 0; j < 8; ++j) {
                const int k1 = 8 * h + j;
                const int k2 = 16 + 8 * h + j;
                float v1 = 0.f, v2 = 0.f;
                if (n < T_) {
                    v1 = __expf(isF ? trans[k1 * T_ + n] : trans[n * T_ + k1]);
                    if (k2 < T_)
                        v2 = __expf(isF ? trans[k2 * T_ + n] : trans[n * T_ + k2]);
                }
                a1e[j] = v1; a2e[j] = v2;
            }
            #pragma unroll
            for (int r = 0; r < 4; ++r) {
                A1p[r] = pkbf(a1e[2 * r], a1e[2 * r + 1]);
                A2p[r] = pkbf(a2e[2 * r], a2e[2 * r + 1]);
            }
        }

        float logacc;
        u32x4 B1p, B2p;
        {
            const int tokI = tok_s[(isF ? 0 : (S_ - 1)) * 32 + n];
            float q1[8], q2[8];
            if (isF) {
                float e1[8], e2[8];
                #pragma unroll
                for (int j = 0; j < 8; ++j) { e1[j] = 0.f; e2[j] = 0.f; }
                float mx = -INFINITY;
                #pragma unroll
                for (int j = 0; j < 8; ++j) {
                    const int r1 = 8 * h + j;
                    e1[j] = start_t[r1] + em_table[tokI * T_ + r1];
                    mx = fmaxf(mx, e1[j]);
                }
                if (h == 0) {
                    #pragma unroll
                    for (int j = 0; j < 8; ++j) {
                        const int r2 = 16 + j;
                        e2[j] = start_t[r2] + em_table[tokI * T_ + r2];
                        mx = fmaxf(mx, e2[j]);
                    }
                }
                mx = fmaxf(mx, __shfl_xor(mx, 32, 64));
                #pragma unroll
                for (int j = 0; j < 8; ++j) {
                    q1[j] = __expf(e1[j] - mx);
                    q2[j] = (h == 0) ? __expf(e2[j] - mx) : 0.f;
                }
                logacc = mx;
            } else {
                #pragma unroll
                for (int j = 0; j < 8; ++j) {
                    const int r1 = 8 * h + j;
                    q1[j] = w_s[tokI * T_ + r1] * __expf(end_t[r1]);
                    const int r2 = 16 + j;
                    q2[j] = (h == 0) ? w_s[tokI * T_ + r2] * __expf(end_t[r2]) : 0.f;
                }
                logacc = 0.f;
            }
            #pragma unroll
            for (int r = 0; r < 4; ++r) {
                B1p[r] = pkbf(q1[2 * r], q1[2 * r + 1]);
                B2p[r] = pkbf(q2[2 * r], q2[2 * r + 1]);
            }
        }

        const int dir  = isF ? 1 : -1;
        const int offi = isF ? 1 : (S_ - 2);

        float4 Wc0, Wc1, Wc2;
        {
            const int tk = tok_s[offi * 32 + n];
            const float* wb = w_s + tk * T_ + 4 * h;
            Wc0 = *(const float4*)(wb);
            Wc1 = *(const float4*)(wb + 8);
            Wc2 = *(const float4*)(wb + 16);
        }

        float d[12];
        for (int s = 1; s <= 63; ++s) {
            const int sn = (s < 63) ? (s + 1) : 63;
            const int tkN = tok_s[(offi + dir * (sn - 1)) * 32 + n];
            const float* wbn = w_s + tkN * T_ + 4 * h;
            const float4 Wn0 = *(const float4*)(wbn);
            const float4 Wn1 = *(const float4*)(wbn + 8);
            const float4 Wn2 = *(const float4*)(wbn + 16);

            facc16 accA, accB;
            #pragma unroll
            for (int r = 0; r < 16; ++r) { accA[r] = 0.f; accB[r] = 0.f; }
            accA = __builtin_amdgcn_mfma_f32_32x32x16_bf16(
                       __builtin_bit_cast(bf8frag, A1p),
                       __builtin_bit_cast(bf8frag, B1p), accA, 0, 0, 0);
            accB = __builtin_amdgcn_mfma_f32_32x32x16_bf16(
                       __builtin_bit_cast(bf8frag, A2p),
                       __builtin_bit_cast(bf8frag, B2p), accB, 0, 0, 0);

            d[0]  = (accA[0]  + accB[0] ) * Wc0.x;
            d[1]  = (accA[1]  + accB[1] ) * Wc0.y;
            d[2]  = (accA[2]  + accB[2] ) * Wc0.z;
            d[3]  = (accA[3]  + accB[3] ) * Wc0.w;
            d[4]  = (accA[4]  + accB[4] ) * Wc1.x;
            d[5]  = (accA[5]  + accB[5] ) * Wc1.y;
            d[6]  = (accA[6]  + accB[6] ) * Wc1.z;
            d[7]  = (accA[7]  + accB[7] ) * Wc1.w;
            d[8]  = (accA[8]  + accB[8] ) * Wc2.x;
            d[9]  = (accA[9]  + accB[9] ) * Wc2.y;
            d[10] = (accA[10] + accB[10]) * Wc2.z;
            d[11] = (accA[11] + accB[11]) * Wc2.w;

            if ((s & 15) == 0 || s == 63) {
                float mx = d[0];
                #pragma unroll
                for (int r = 1; r < 12; ++r) mx = fmaxf(mx, d[r]);
                mx = fmaxf(mx, __shfl_xor(mx, 32, 64));
                const float inv = 1.0f / mx;
                #pragma unroll
                for (int r = 0; r < 12; ++r) d[r] *= inv;
                logacc += __logf(mx);
            }

            const unsigned P0 = pkbf(d[0], d[1]),  P1 = pkbf(d[2], d[3]);
            const unsigned P2 = pkbf(d[4], d[5]),  P3 = pkbf(d[6], d[7]);
            const unsigned P4 = pkbf(d[8], d[9]),  P5 = pkbf(d[10], d[11]);
            const unsigned XP0 = (unsigned)__shfl_xor((int)P0, 32, 64);
            const unsigned XP1 = (unsigned)__shfl_xor((int)P1, 32, 64);
            const unsigned XP2 = (unsigned)__shfl_xor((int)P2, 32, 64);
            const unsigned XP3 = (unsigned)__shfl_xor((int)P3, 32, 64);
            const unsigned XP4 = (unsigned)__shfl_xor((int)P4, 32, 64);
            const unsigned XP5 = (unsigned)__shfl_xor((int)P5, 32, 64);
            B1p[0] = h ? XP2 : P0;  B1p[1] = h ? XP3 : P1;
            B1p[2] = h ? P2  : XP0; B1p[3] = h ? P3  : XP1;
            B2p[0] = h ? 0u  : P4;  B2p[1] = h ? 0u  : P5;
            B2p[2] = h ? 0u  : XP4; B2p[3] = h ? 0u  : XP5;

            Wc0 = Wn0; Wc1 = Wn1; Wc2 = Wn2;
        }

        if (!isF) {
            #pragma unroll
            for (int r = 0; r < 12; ++r) meet_s[lane * 12 + r] = d[r];
            logb_s[lane] = logacc;
        }
        __syncthreads();
        if (isF) {
            facc16 accA, accB;
            #pragma unroll
            for (int r = 0; r < 16; ++r) { accA[r] = 0.f; accB[r] = 0.f; }
            accA = __builtin_amdgcn_mfma_f32_32x32x16_bf16(
                       __builtin_bit_cast(bf8frag, A1p),
                       __builtin_bit_cast(bf8frag, B1p), accA, 0, 0, 0);
            accB = __builtin_amdgcn_mfma_f32_32x32x16_bf16(
                       __builtin_bit_cast(bf8frag, A2p),
                       __builtin_bit_cast(bf8frag, B2p), accB, 0, 0, 0);
            float dot = 0.f;
            #pragma unroll
            for (int r = 0; r < 12; ++r)
                dot = fmaf(accA[r] + accB[r], meet_s[lane * 12 + r], dot);
            dot += __shfl_xor(dot, 32, 64);
            const float denom = logacc + logb_s[lane] + __logf(dot);
            float val = 0.f;
            if (h == 0)
                val = (denom - gp_s[n]) * (1.0f / (float)B_);
            #pragma unroll
            for (int off = 32; off; off >>= 1)
                val += __shfl_xor(val, off, 64);
            if (lane == 0) atomicAdd(out, val);
        }
    } else {
        const int t2 = tid - 128;
        const int n = t2 & 31;
        const int r = t2 >> 5;
        const int b = g * 32 + n;
        const int* __restrict__ lrow = labels + (size_t)b * S_;
        float gp = 0.f;
        for (int i = 0; i < 32; ++i) {
            const int s = r * 32 + i;
            const int tk = tok_s[s * 32 + n];
            const int ls = lrow[s];
            gp += em_table[tk * T_ + ls];
            if (s >= 1) gp -= emax_arr[tk];
            if (s < S_ - 1) gp += trans[ls * T_ + lrow[s + 1]];
            if (s == 0) gp += start_t[ls];
            if (s == S_ - 1) gp += end_t[ls];
        }
        atomicAdd(&gp_s[n], gp);
        __syncthreads();
    }
}

// ---------------------------------------------------------------------------
extern "C" void kernel_launch(void* const* d_in, const int* in_sizes, int n_in,
                              void* d_out, int out_size, void* d_ws, size_t ws_size,
                              hipStream_t stream) {
    const int*   seq     = (const int*)d_in[0];
    const int*   labels  = (const int*)d_in[1];
    // d_in[2] true_lengths: unused by the reference forward
    const float* emb     = (const float*)d_in[3];
    const float* w1      = (const float*)d_in[4];
    const float* b1      = (const float*)d_in[5];
    const float* w2      = (const float*)d_in[6];
    const float* b2      = (const float*)d_in[7];
    const float* start_t = (const float*)d_in[8];
    const float* end_t   = (const float*)d_in[9];
    const float* trans   = (const float*)d_in[10];

    float* ws            = (float*)d_ws;
    float* h_ws          = ws + OFF_H;
    float* em_table      = ws + OFF_EM;
    float* w_table       = ws + OFF_W;
    float* emax_arr      = ws + OFF_MX;
    float* out           = (float*)d_out;

    mlp1_kernel<<<112, 256, 0, stream>>>(emb, w1, b1, h_ws, out);
    emis_kernel<<<V_ / 8, 256, 0, stream>>>(h_ws, w2, b2, em_table, w_table, emax_arr);
    crf_kernel<<<B_ / 32, 256, 0, stream>>>(seq, labels, start_t, end_t, trans,
                                            em_table, w_table, emax_arr, out);
}

// Round 17
// 108.844 us; speedup vs baseline: 1.0188x; 1.0188x over previous
//
#include <hip/hip_runtime.h>
#include <math.h>

#define PAD_IDX 0
#define BIGV 10000.0f
constexpr int B_ = 1024, S_ = 128, V_ = 200, E_ = 512, H_ = 512, T_ = 24;

// ws layout (float offsets):
constexpr int OFF_H  = 262144;   // h_ws   [200][512]
constexpr int OFF_EM = 364544;   // em_tab [200][24]
constexpr int OFF_W  = 369344;   // w_tab  [200][24]
constexpr int OFF_MX = 374144;   // emax   [200]

typedef __attribute__((ext_vector_type(8)))  short    bf8frag;   // 8 bf16
typedef __attribute__((ext_vector_type(16))) float    facc16;    // MFMA C/D
typedef __attribute__((ext_vector_type(4)))  unsigned u32x4;

__device__ __forceinline__ unsigned pkbf(float lo, float hi) {
    const unsigned a = __float_as_uint(lo), b = __float_as_uint(hi);
    return ((a + 0x8000u) >> 16) | ((b + 0x8000u) & 0xffff0000u);
}

// ---------------------------------------------------------------------------
// Kernel M1: h = relu(emb @ w1^T + b1) on the matrix pipe (R15, verified
// 109.0us / absmax 0.0). R16's emis-MFMA port regressed (staging + 25-block
// latency > MFMA gain) — this file is the byte-identical R15 best.
// ---------------------------------------------------------------------------
__global__ __launch_bounds__(256) void mlp1_kernel(
    const float* __restrict__ emb, const float* __restrict__ w1,
    const float* __restrict__ b1, float* __restrict__ h_ws,
    float* __restrict__ out)
{
    __shared__ unsigned w1b[256][32];     // B operand: [kp][t-col]
    __shared__ unsigned embb[256][32];    // A operand: [kp][v-row]
    __shared__ float    part[4][64][17];  // K-split partials (+1 pad)
    const int tid = threadIdx.x;
    const int vt = blockIdx.x % 7, tt = blockIdx.x / 7;
    const int v0 = vt * 32, t0 = tt * 32;

    if (blockIdx.x == 0 && tid == 0) out[0] = 0.f;   // crf atomic accumulator

    {
        const int row = tid >> 3;          // 0..31
        const int seg = tid & 7;           // 64 floats each
        {
            const float* __restrict__ src = w1 + (size_t)(t0 + row) * E_ + seg * 64;
            #pragma unroll
            for (int i = 0; i < 16; ++i) {
                const float4 f = *(const float4*)(src + i * 4);
                const int kp = seg * 32 + i * 2;
                w1b[kp][row]     = pkbf(f.x, f.y);
                w1b[kp + 1][row] = pkbf(f.z, f.w);
            }
        }
        const int v = v0 + row;
        if (v < V_) {
            const float* __restrict__ src = emb + (size_t)v * E_ + seg * 64;
            #pragma unroll
            for (int i = 0; i < 16; ++i) {
                const float4 f = *(const float4*)(src + i * 4);
                const int kp = seg * 32 + i * 2;
                embb[kp][row]     = pkbf(f.x, f.y);
                embb[kp + 1][row] = pkbf(f.z, f.w);
            }
        } else {
            #pragma unroll
            for (int i = 0; i < 16; ++i) {
                const int kp = seg * 32 + i * 2;
                embb[kp][row] = 0u; embb[kp + 1][row] = 0u;
            }
        }
    }
    __syncthreads();

    {
        const int wave = tid >> 6, lane = tid & 63;
        const int mn = lane & 31, h2 = lane >> 5;
        facc16 acc;
        #pragma unroll
        for (int r = 0; r < 16; ++r) acc[r] = 0.f;
        #pragma unroll
        for (int c = 0; c < 8; ++c) {
            const int kp = wave * 64 + c * 8 + 4 * h2;
            u32x4 Af, Bf;
            #pragma unroll
            for (int r = 0; r < 4; ++r) {
                Af[r] = embb[kp + r][mn];
                Bf[r] = w1b[kp + r][mn];
            }
            acc = __builtin_amdgcn_mfma_f32_32x32x16_bf16(
                      __builtin_bit_cast(bf8frag, Af),
                      __builtin_bit_cast(bf8frag, Bf), acc, 0, 0, 0);
        }
        #pragma unroll
        for (int r = 0; r < 16; ++r) part[wave][lane][r] = acc[r];
    }
    __syncthreads();

    {
        const int l = tid & 63, rg = tid >> 6;
        const int col = l & 31, hh = l >> 5;
        const float bb = b1[t0 + col];
        #pragma unroll
        for (int i = 0; i < 4; ++i) {
            const int r = rg * 4 + i;
            const float s = (part[0][l][r] + part[1][l][r])
                          + (part[2][l][r] + part[3][l][r]);
            const int vrow = (r & 3) + 8 * (r >> 2) + 4 * hh;
            const int v = v0 + vrow;
            if (v < V_)
                h_ws[(size_t)v * H_ + t0 + col] = fmaxf(s + bb, 0.f);
        }
    }
}

// ---------------------------------------------------------------------------
// Kernel A2: em_table / w_table / emax (proven R11/R14/R15, unchanged).
// 200 blocks; launch-latency-dominated — R16 showed MFMA port regresses.
// ---------------------------------------------------------------------------
__global__ __launch_bounds__(256) void emis_kernel(
    const float* __restrict__ h_ws, const float* __restrict__ w2,
    const float* __restrict__ b2, float* __restrict__ em_table,
    float* __restrict__ w_table, float* __restrict__ emax_arr)
{
    __shared__ float em_row[32];
    const int v = blockIdx.x;
    const int t = threadIdx.x;
    const int wave = t >> 6, lane = t & 63;
    const float* __restrict__ hrow = h_ws + (size_t)v * H_;
    for (int jj2 = 0; jj2 < 6; ++jj2) {
        const int jo = wave * 6 + jj2;
        float part = 0.f;
        #pragma unroll
        for (int m = 0; m < H_ / 64; ++m) {
            const int k = lane + m * 64;
            part = fmaf(hrow[k], w2[(size_t)jo * H_ + k], part);
        }
        #pragma unroll
        for (int off = 32; off; off >>= 1)
            part += __shfl_xor(part, off, 64);
        if (lane == 0) {
            float val = fmaxf(part + b2[jo], 0.f);
            if (v == 0 && jo == PAD_IDX) val += BIGV;
            em_row[jo] = val;
        }
    }
    __syncthreads();
    if (t < 32) {
        float x = (t < T_) ? em_row[t] : -INFINITY;
        float mx = x;
        #pragma unroll
        for (int off = 16; off; off >>= 1)
            mx = fmaxf(mx, __shfl_xor(mx, off, 32));
        if (t < T_) {
            em_table[v * T_ + t] = x;
            w_table[v * T_ + t]  = __expf(x - mx);
        }
        if (t == 0) emax_arr[v] = mx;
    }
}

// ---------------------------------------------------------------------------
// Kernel B: crf + gold fused (R14/R15, passed absmax 0.0, unchanged).
// Waves 0-1: MFMA fwd/bwd meet-in-middle chain; waves 2-3: gold, concurrent.
// ---------------------------------------------------------------------------
__global__ __launch_bounds__(256) void crf_kernel(
    const int* __restrict__ seq, const int* __restrict__ labels,
    const float* __restrict__ start_t, const float* __restrict__ end_t,
    const float* __restrict__ trans, const float* __restrict__ em_table,
    const float* __restrict__ w_table, const float* __restrict__ emax_arr,
    float* __restrict__ out)
{
    __shared__ __align__(16) float w_s[V_ * T_];
    __shared__ int   tok_s[S_ * 32];
    __shared__ float meet_s[64 * 12];
    __shared__ float logb_s[64];
    __shared__ float gp_s[32];
    const int tid = threadIdx.x;
    const int g = blockIdx.x;

    for (int i = tid; i < V_ * T_ / 4; i += 256)
        ((float4*)w_s)[i] = ((const float4*)w_table)[i];
    {
        const int bq = tid & 31, c = tid >> 5;
        const int* __restrict__ src = seq + (size_t)(g * 32 + bq) * S_ + c * 16;
        #pragma unroll
        for (int i = 0; i < 16; ++i)
            tok_s[(c * 16 + i) * 32 + bq] = src[i];
    }
    if (tid < 32) gp_s[tid] = 0.f;
    __syncthreads();

    if (tid < 128) {
        const bool isF = (tid < 64);
        const int lane = tid & 63;
        const int n = lane & 31;
        const int h = lane >> 5;

        u32x4 A1p, A2p;
        {
            float a1e[8], a2e[8];
            #pragma unroll
            for (int j = 0; j < 8; ++j) {
                const int k1 = 8 * h + j;
                const int k2 = 16 + 8 * h + j;
                float v1 = 0.f, v2 = 0.f;
                if (n < T_) {
                    v1 = __expf(isF ? trans[k1 * T_ + n] : trans[n * T_ + k1]);
                    if (k2 < T_)
                        v2 = __expf(isF ? trans[k2 * T_ + n] : trans[n * T_ + k2]);
                }
                a1e[j] = v1; a2e[j] = v2;
            }
            #pragma unroll
            for (int r = 0; r < 4; ++r) {
                A1p[r] = pkbf(a1e[2 * r], a1e[2 * r + 1]);
                A2p[r] = pkbf(a2e[2 * r], a2e[2 * r + 1]);
            }
        }

        float logacc;
        u32x4 B1p, B2p;
        {
            const int tokI = tok_s[(isF ? 0 : (S_ - 1)) * 32 + n];
            float q1[8], q2[8];
            if (isF) {
                float e1[8], e2[8];
                #pragma unroll
                for (int j = 0; j < 8; ++j) { e1[j] = 0.f; e2[j] = 0.f; }
                float mx = -INFINITY;
                #pragma unroll
                for (int j = 0; j < 8; ++j) {
                    const int r1 = 8 * h + j;
                    e1[j] = start_t[r1] + em_table[tokI * T_ + r1];
                    mx = fmaxf(mx, e1[j]);
                }
                if (h == 0) {
                    #pragma unroll
                    for (int j = 0; j < 8; ++j) {
                        const int r2 = 16 + j;
                        e2[j] = start_t[r2] + em_table[tokI * T_ + r2];
                        mx = fmaxf(mx, e2[j]);
                    }
                }
                mx = fmaxf(mx, __shfl_xor(mx, 32, 64));
                #pragma unroll
                for (int j = 0; j < 8; ++j) {
                    q1[j] = __expf(e1[j] - mx);
                    q2[j] = (h == 0) ? __expf(e2[j] - mx) : 0.f;
                }
                logacc = mx;
            } else {
                #pragma unroll
                for (int j = 0; j < 8; ++j) {
                    const int r1 = 8 * h + j;
                    q1[j] = w_s[tokI * T_ + r1] * __expf(end_t[r1]);
                    const int r2 = 16 + j;
                    q2[j] = (h == 0) ? w_s[tokI * T_ + r2] * __expf(end_t[r2]) : 0.f;
                }
                logacc = 0.f;
            }
            #pragma unroll
            for (int r = 0; r < 4; ++r) {
                B1p[r] = pkbf(q1[2 * r], q1[2 * r + 1]);
                B2p[r] = pkbf(q2[2 * r], q2[2 * r + 1]);
            }
        }

        const int dir  = isF ? 1 : -1;
        const int offi = isF ? 1 : (S_ - 2);

        float4 Wc0, Wc1, Wc2;
        {
            const int tk = tok_s[offi * 32 + n];
            const float* wb = w_s + tk * T_ + 4 * h;
            Wc0 = *(const float4*)(wb);
            Wc1 = *(const float4*)(wb + 8);
            Wc2 = *(const float4*)(wb + 16);
        }

        float d[12];
        for (int s = 1; s <= 63; ++s) {
            const int sn = (s < 63) ? (s + 1) : 63;
            const int tkN = tok_s[(offi + dir * (sn - 1)) * 32 + n];
            const float* wbn = w_s + tkN * T_ + 4 * h;
            const float4 Wn0 = *(const float4*)(wbn);
            const float4 Wn1 = *(const float4*)(wbn + 8);
            const float4 Wn2 = *(const float4*)(wbn + 16);

            facc16 accA, accB;
            #pragma unroll
            for (int r = 0; r < 16; ++r) { accA[r] = 0.f; accB[r] = 0.f; }
            accA = __builtin_amdgcn_mfma_f32_32x32x16_bf16(
                       __builtin_bit_cast(bf8frag, A1p),
                       __builtin_bit_cast(bf8frag, B1p), accA, 0, 0, 0);
            accB = __builtin_amdgcn_mfma_f32_32x32x16_bf16(
                       __builtin_bit_cast(bf8frag, A2p),
                       __builtin_bit_cast(bf8frag, B2p), accB, 0, 0, 0);

            d[0]  = (accA[0]  + accB[0] ) * Wc0.x;
            d[1]  = (accA[1]  + accB[1] ) * Wc0.y;
            d[2]  = (accA[2]  + accB[2] ) * Wc0.z;
            d[3]  = (accA[3]  + accB[3] ) * Wc0.w;
            d[4]  = (accA[4]  + accB[4] ) * Wc1.x;
            d[5]  = (accA[5]  + accB[5] ) * Wc1.y;
            d[6]  = (accA[6]  + accB[6] ) * Wc1.z;
            d[7]  = (accA[7]  + accB[7] ) * Wc1.w;
            d[8]  = (accA[8]  + accB[8] ) * Wc2.x;
            d[9]  = (accA[9]  + accB[9] ) * Wc2.y;
            d[10] = (accA[10] + accB[10]) * Wc2.z;
            d[11] = (accA[11] + accB[11]) * Wc2.w;

            if ((s & 15) == 0 || s == 63) {
                float mx = d[0];
                #pragma unroll
                for (int r = 1; r < 12; ++r) mx = fmaxf(mx, d[r]);
                mx = fmaxf(mx, __shfl_xor(mx, 32, 64));
                const float inv = 1.0f / mx;
                #pragma unroll
                for (int r = 0; r < 12; ++r) d[r] *= inv;
                logacc += __logf(mx);
            }

            const unsigned P0 = pkbf(d[0], d[1]),  P1 = pkbf(d[2], d[3]);
            const unsigned P2 = pkbf(d[4], d[5]),  P3 = pkbf(d[6], d[7]);
            const unsigned P4 = pkbf(d[8], d[9]),  P5 = pkbf(d[10], d[11]);
            const unsigned XP0 = (unsigned)__shfl_xor((int)P0, 32, 64);
            const unsigned XP1 = (unsigned)__shfl_xor((int)P1, 32, 64);
            const unsigned XP2 = (unsigned)__shfl_xor((int)P2, 32, 64);
            const unsigned XP3 = (unsigned)__shfl_xor((int)P3, 32, 64);
            const unsigned XP4 = (unsigned)__shfl_xor((int)P4, 32, 64);
            const unsigned XP5 = (unsigned)__shfl_xor((int)P5, 32, 64);
            B1p[0] = h ? XP2 : P0;  B1p[1] = h ? XP3 : P1;
            B1p[2] = h ? P2  : XP0; B1p[3] = h ? P3  : XP1;
            B2p[0] = h ? 0u  : P4;  B2p[1] = h ? 0u  : P5;
            B2p[2] = h ? 0u  : XP4; B2p[3] = h ? 0u  : XP5;

            Wc0 = Wn0; Wc1 = Wn1; Wc2 = Wn2;
        }

        if (!isF) {
            #pragma unroll
            for (int r = 0; r < 12; ++r) meet_s[lane * 12 + r] = d[r];
            logb_s[lane] = logacc;
        }
        __syncthreads();
        if (isF) {
            facc16 accA, accB;
            #pragma unroll
            for (int r = 0; r < 16; ++r) { accA[r] = 0.f; accB[r] = 0.f; }
            accA = __builtin_amdgcn_mfma_f32_32x32x16_bf16(
                       __builtin_bit_cast(bf8frag, A1p),
                       __builtin_bit_cast(bf8frag, B1p), accA, 0, 0, 0);
            accB = __builtin_amdgcn_mfma_f32_32x32x16_bf16(
                       __builtin_bit_cast(bf8frag, A2p),
                       __builtin_bit_cast(bf8frag, B2p), accB, 0, 0, 0);
            float dot = 0.f;
            #pragma unroll
            for (int r = 0; r < 12; ++r)
                dot = fmaf(accA[r] + accB[r], meet_s[lane * 12 + r], dot);
            dot += __shfl_xor(dot, 32, 64);
            const float denom = logacc + logb_s[lane] + __logf(dot);
            float val = 0.f;
            if (h == 0)
                val = (denom - gp_s[n]) * (1.0f / (float)B_);
            #pragma unroll
            for (int off = 32; off; off >>= 1)
                val += __shfl_xor(val, off, 64);
            if (lane == 0) atomicAdd(out, val);
        }
    } else {
        const int t2 = tid - 128;
        const int n = t2 & 31;
        const int r = t2 >> 5;
        const int b = g * 32 + n;
        const int* __restrict__ lrow = labels + (size_t)b * S_;
        float gp = 0.f;
        for (int i = 0; i < 32; ++i) {
            const int s = r * 32 + i;
            const int tk = tok_s[s * 32 + n];
            const int ls = lrow[s];
            gp += em_table[tk * T_ + ls];
            if (s >= 1) gp -= emax_arr[tk];
            if (s < S_ - 1) gp += trans[ls * T_ + lrow[s + 1]];
            if (s == 0) gp += start_t[ls];
            if (s == S_ - 1) gp += end_t[ls];
        }
        atomicAdd(&gp_s[n], gp);
        __syncthreads();
    }
}

// ---------------------------------------------------------------------------
extern "C" void kernel_launch(void* const* d_in, const int* in_sizes, int n_in,
                              void* d_out, int out_size, void* d_ws, size_t ws_size,
                              hipStream_t stream) {
    const int*   seq     = (const int*)d_in[0];
    const int*   labels  = (const int*)d_in[1];
    // d_in[2] true_lengths: unused by the reference forward
    const float* emb     = (const float*)d_in[3];
    const float* w1      = (const float*)d_in[4];
    const float* b1      = (const float*)d_in[5];
    const float* w2      = (const float*)d_in[6];
    const float* b2      = (const float*)d_in[7];
    const float* start_t = (const float*)d_in[8];
    const float* end_t   = (const float*)d_in[9];
    const float* trans   = (const float*)d_in[10];

    float* ws            = (float*)d_ws;
    float* h_ws          = ws + OFF_H;
    float* em_table      = ws + OFF_EM;
    float* w_table       = ws + OFF_W;
    float* emax_arr      = ws + OFF_MX;
    float* out           = (float*)d_out;

    mlp1_kernel<<<112, 256, 0, stream>>>(emb, w1, b1, h_ws, out);
    emis_kernel<<<V_, 256, 0, stream>>>(h_ws, w2, b2, em_table, w_table, emax_arr);
    crf_kernel<<<B_ / 32, 256, 0, stream>>>(seq, labels, start_t, end_t, trans,
                                            em_table, w_table, emax_arr, out);
}